// Round 9
// baseline (1057.116 us; speedup 1.0000x reference)
//
#include <hip/hip_runtime.h>

typedef unsigned short u16;
typedef unsigned int u32;
typedef _Float16 h4 __attribute__((ext_vector_type(4)));
typedef _Float16 h8 __attribute__((ext_vector_type(8)));
typedef float f32x4 __attribute__((ext_vector_type(4)));

#define MFMA16(a, b, c) __builtin_amdgcn_mfma_f32_16x16x32_f16((a), (b), (c), 0, 0, 0)

__device__ __forceinline__ float wsum(float v) {
  #pragma unroll
  for (int o = 32; o > 0; o >>= 1) v += __shfl_down(v, o);
  return __shfl(v, 0);
}

// ---------- prep: qkv_w f32 [256k][768c] -> fp16 [row = h*96 + mat*32 + cc][256 k] ----------
__global__ void k_prep_qkv(const float* __restrict__ w, _Float16* __restrict__ o) {
  const int e = blockIdx.x * 256 + threadIdx.x;   // 768*256
  const int r = e >> 8, k = e & 255;
  const int h = r / 96, rem = r - h * 96;
  const int mat = rem >> 5, cc = rem & 31;
  o[e] = (_Float16)w[k * 768 + mat * 256 + h * 32 + cc];
}

// ---------- prep: proj_w f32 [256 in][256 out] -> fp16 [out][in] (k-contiguous) ----------
__global__ void k_prep_pw(const float* __restrict__ w, _Float16* __restrict__ o) {
  const int e = blockIdx.x * 256 + threadIdx.x;   // 256*256
  const int oc = e >> 8, ic = e & 255;
  o[e] = (_Float16)w[ic * 256 + oc];
}

// ---------- prep: fc1_w f32 [256k][1024c] -> fp16 [col][256 k] ----------
__global__ void k_prep_w1(const float* __restrict__ w, _Float16* __restrict__ o) {
  const int e = blockIdx.x * 256 + threadIdx.x;   // 1024*256
  const int col = e >> 8, k = e & 255;
  o[e] = (_Float16)w[k * 1024 + col];
}

// ---------- prep: fc2_w f32 [1024k][256c] -> fp16 [col][1024 k] ----------
__global__ void k_prep_w2(const float* __restrict__ w, _Float16* __restrict__ o) {
  const int e = blockIdx.x * 256 + threadIdx.x;   // 256*1024
  const int oc = e >> 10, k = e & 1023;
  o[e] = (_Float16)w[k * 256 + oc];
}

// ---------- prep: btab[h][e] = rtab[rpi[e]*8 + h] ----------
__global__ void k_prep_btab(const int* __restrict__ rpi, const float* __restrict__ rtab,
                            float* __restrict__ btab) {
  const int e = blockIdx.x * 256 + threadIdx.x;
  if (e < 2401) {
    const int idx = rpi[e];
    #pragma unroll
    for (int h = 0; h < 8; ++h) btab[h * 2401 + e] = rtab[idx * 8 + h];
  }
}

// ---------- fused block kernel: 2048 blocks x 256 threads (4 waves), 80 KiB -> 2 blocks/CU ----
// Wave w handles heads {w, w+4} sequentially.
// Phase A:
//   ZN   [0,32768)      : LN1 out fp16 [64][512B], swz ^((row&7)<<4). O overlays after b2.
//   priv 32768+w*12288  : Q(4K)/K(4K)/V(4K) per wave; P overlays Q+K. Reused across 2 heads.
// Phase B:
//   ZN2  [0,32768)      : LN2 out fp16 (over dead O)
//   x1   [32768,65536)  : fp16 [64][512B] swz ^((tok&7)<<4) (over dead priv w0/w1/part w2)
//   H    [65536,81920)  : fp16 [64][256B] swz ^((tok&15)<<4), hidden chunk = 128
#define X1_OFF 32768
#define H_OFF  65536

__global__ __launch_bounds__(256, 2) void k_blk(
    const float* __restrict__ x, const _Float16* __restrict__ wsq,
    const _Float16* __restrict__ pwh, const float* __restrict__ qkvb,
    const float* __restrict__ g1, const float* __restrict__ b1,
    const float* __restrict__ temp, const float* __restrict__ btab,
    const float* __restrict__ amask, const float* __restrict__ pb,
    const float* __restrict__ g2, const float* __restrict__ b2,
    const _Float16* __restrict__ w1h, const float* __restrict__ fb1,
    const _Float16* __restrict__ w2h, const float* __restrict__ fb2,
    float* __restrict__ io) {
  __shared__ __align__(16) char smem[81920];
  const int tid = threadIdx.x;
  const int lane = tid & 63, w = tid >> 6;      // w = 0..3
  const int lr = lane & 15, lk = lane >> 4;
  const int win = blockIdx.x;
  const int bb = win >> 6, wimg = win & 63;
  const int hb = wimg >> 3, wb = wimg & 7;
  const float scale = expf(temp[0]);
  char* const pwv = smem + 32768 + w * 12288;   // wave-private scratch (phase A)

  // --- LN1 at shifted source coords (roll(-3)) -> ZN fp16 ---
  {
    const float4 gz = ((const float4*)g1)[lane];
    const float4 bz = ((const float4*)b1)[lane];
    for (int n = w; n < 49; n += 4) {
      int i = n / 7, j = n - 7 * i;
      int rs = hb * 7 + i + 3; if (rs >= 56) rs -= 56;
      int cs = wb * 7 + j + 3; if (cs >= 56) cs -= 56;
      const float4 p = ((const float4*)(x + ((size_t)bb * 3136 + rs * 56 + cs) * 256))[lane];
      float mean = wsum(p.x + p.y + p.z + p.w) * (1.f / 256.f);
      float d0 = p.x - mean, d1 = p.y - mean, d2 = p.z - mean, d3 = p.w - mean;
      float var = wsum(d0 * d0 + d1 * d1 + d2 * d2 + d3 * d3) * (1.f / 256.f);
      float rstd = rsqrtf(var + 1e-6f);
      h4 z;
      z[0] = (_Float16)(d0 * rstd * gz.x + bz.x);
      z[1] = (_Float16)(d1 * rstd * gz.y + bz.y);
      z[2] = (_Float16)(d2 * rstd * gz.z + bz.z);
      z[3] = (_Float16)(d3 * rstd * gz.w + bz.w);
      *(h4*)(smem + ((n * 512 + lane * 8) ^ ((n & 7) << 4))) = z;
    }
  }
  __syncthreads();   // b1: ZN ready

  f32x4 oA0[4], oA1[4], oB0[4], oB1[4];   // PV outputs for the wave's two heads

  // ---- per-head pipeline (wave-private after ZN; no barriers inside) ----
  auto do_head = [&](const int h, f32x4 (&po0)[4], f32x4 (&po1)[4]) {
    f32x4 zz = {0.f, 0.f, 0.f, 0.f};
    // qkv: (64x256)@(256x96), 192 MFMA
    {
      f32x4 acc[4][6];
      #pragma unroll
      for (int t = 0; t < 4; ++t)
        #pragma unroll
        for (int c = 0; c < 6; ++c) acc[t][c] = zz;
      const _Float16* wr[6];
      #pragma unroll
      for (int c = 0; c < 6; ++c)
        wr[c] = wsq + ((size_t)(h * 96 + c * 16 + lr) * 256 + lk * 8);
      const int swzA = (lr & 7) << 4;
      #pragma unroll
      for (int ks = 0; ks < 8; ++ks) {
        const int ko = ks * 64 + lk * 16;
        h8 a[4];
        #pragma unroll
        for (int t = 0; t < 4; ++t)
          a[t] = *(const h8*)(smem + (((t * 16 + lr) * 512 + ko) ^ swzA));
        h8 b[6];
        #pragma unroll
        for (int c = 0; c < 6; ++c) b[c] = *(const h8*)(wr[c] + ks * 32);
        #pragma unroll
        for (int t = 0; t < 4; ++t)
          #pragma unroll
          for (int c = 0; c < 6; ++c) acc[t][c] = MFMA16(a[t], b[c], acc[t][c]);
      }
      // D -> priv Q/K/V (pad tokens >=49 -> 0)
      #pragma unroll
      for (int c = 0; c < 6; ++c) {
        const int mat = c >> 1;
        const int cc = (c & 1) * 16 + lr;
        const float bias = qkvb[mat * 256 + h * 32 + cc];
        #pragma unroll
        for (int t = 0; t < 4; ++t) {
          const int tok0 = t * 16 + lk * 4;
          if (mat == 2) {
            h4 pk;
            #pragma unroll
            for (int r = 0; r < 4; ++r) {
              float v = (tok0 + r < 49) ? (acc[t][c][r] + bias) : 0.f;
              pk[r] = (_Float16)v;
            }
            *(h4*)(pwv + 8192 + (tok0 >> 3) * 512 + cc * 16 + (tok0 & 7) * 2) = pk;
          } else {
            char* base = pwv + (mat ? 4096 : 0);
            const float mult = mat ? 1.f : scale;
            #pragma unroll
            for (int r = 0; r < 4; ++r) {
              const int tok = tok0 + r;
              float v = (tok < 49) ? (acc[t][c][r] + bias) * mult : 0.f;
              *(_Float16*)(base + ((tok * 64 + cc * 2) ^ (((tok >> 1) & 3) << 4))) = (_Float16)v;
            }
          }
        }
      }
    }
    // scores + in-register softmax -> P (overlays Q/K)
    {
      f32x4 s[4][4];
      #pragma unroll
      for (int t = 0; t < 4; ++t)
        #pragma unroll
        for (int m = 0; m < 4; ++m) s[t][m] = zz;
      const int swzq = ((lr >> 1) & 3) << 4;
      h8 aq[4], bk[4];
      #pragma unroll
      for (int t = 0; t < 4; ++t) {
        aq[t] = *(const h8*)(pwv + (((t * 16 + lr) * 64 + lk * 16) ^ swzq));
        bk[t] = *(const h8*)(pwv + 4096 + (((t * 16 + lr) * 64 + lk * 16) ^ swzq));
      }
      #pragma unroll
      for (int t = 0; t < 4; ++t)
        #pragma unroll
        for (int m = 0; m < 4; ++m) s[t][m] = MFMA16(aq[t], bk[m], s[t][m]);

      const float* bt = btab + (size_t)h * 2401;
      const float* am = amask + (size_t)wimg * 2401;
      #pragma unroll
      for (int t = 0; t < 4; ++t) {
        #pragma unroll
        for (int r = 0; r < 4; ++r) {
          const int n = t * 16 + lk * 4 + r;
          if (n < 49) {
            #pragma unroll
            for (int m = 0; m < 4; ++m) {
              const int mm = m * 16 + lr;
              float sv;
              if (mm >= 49) sv = -1e38f;
              else {
                sv = s[t][m][r];
                if (mm == n) sv = -1e30f;
                const int ee = n * 49 + mm;
                sv += bt[ee] + am[ee];
              }
              s[t][m][r] = sv;
            }
          } else {
            #pragma unroll
            for (int m = 0; m < 4; ++m) s[t][m][r] = 0.f;
          }
        }
      }
      #pragma unroll
      for (int t = 0; t < 4; ++t) {
        #pragma unroll
        for (int r = 0; r < 4; ++r) {
          float mx = fmaxf(fmaxf(s[t][0][r], s[t][1][r]), fmaxf(s[t][2][r], s[t][3][r]));
          mx = fmaxf(mx, __shfl_xor(mx, 1));
          mx = fmaxf(mx, __shfl_xor(mx, 2));
          mx = fmaxf(mx, __shfl_xor(mx, 4));
          mx = fmaxf(mx, __shfl_xor(mx, 8));
          float e0 = expf(s[t][0][r] - mx), e1 = expf(s[t][1][r] - mx);
          float e2 = expf(s[t][2][r] - mx), e3 = expf(s[t][3][r] - mx);
          float sm = e0 + e1 + e2 + e3;
          sm += __shfl_xor(sm, 1);
          sm += __shfl_xor(sm, 2);
          sm += __shfl_xor(sm, 4);
          sm += __shfl_xor(sm, 8);
          const float inv = 1.f / sm;
          const int n = t * 16 + lk * 4 + r;
          const int sw = (n & 7) << 4;
          char* pr = pwv + n * 128;
          *(_Float16*)(pr + ((lr * 2) ^ sw))        = (_Float16)(e0 * inv);
          *(_Float16*)(pr + (((16 + lr) * 2) ^ sw)) = (_Float16)(e1 * inv);
          *(_Float16*)(pr + (((32 + lr) * 2) ^ sw)) = (_Float16)(e2 * inv);
          *(_Float16*)(pr + (((48 + lr) * 2) ^ sw)) = (_Float16)(e3 * inv);
        }
      }
    }
    // PV -> registers
    {
      #pragma unroll
      for (int t = 0; t < 4; ++t) { po0[t] = zz; po1[t] = zz; }
      const int swzp = (lr & 7) << 4;
      #pragma unroll
      for (int ks = 0; ks < 2; ++ks) {
        h8 bv0 = *(const h8*)(pwv + 8192 + (ks * 4 + lk) * 512 + lr * 16);
        h8 bv1 = *(const h8*)(pwv + 8192 + (ks * 4 + lk) * 512 + (16 + lr) * 16);
        #pragma unroll
        for (int t = 0; t < 4; ++t) {
          h8 ap = *(const h8*)(pwv + (((t * 16 + lr) * 128 + ks * 64 + lk * 16) ^ swzp));
          po0[t] = MFMA16(ap, bv0, po0[t]);
          po1[t] = MFMA16(ap, bv1, po1[t]);
        }
      }
    }
  };

  do_head(w, oA0, oA1);
  do_head(w + 4, oB0, oB1);
  __syncthreads();   // b2: all ZN reads done -> O may overlay ZN

  // ---- write both heads' O slices into shared O [64][512B] (ZN region) ----
  {
    auto write_o = [&](const int h, f32x4 (&po0)[4], f32x4 (&po1)[4]) {
      #pragma unroll
      for (int t = 0; t < 4; ++t) {
        #pragma unroll
        for (int r = 0; r < 4; ++r) {
          const int tok = t * 16 + lk * 4 + r;
          const int sw = (tok & 7) << 4;
          char* orow = smem + tok * 512;
          *(_Float16*)(orow + (((h * 32 + lr) * 2) ^ sw))      = (_Float16)po0[t][r];
          *(_Float16*)(orow + (((h * 32 + 16 + lr) * 2) ^ sw)) = (_Float16)po1[t][r];
        }
      }
    };
    write_o(w, oA0, oA1);
    write_o(w + 4, oB0, oB1);
  }
  __syncthreads();   // b3: full O ready; priv dead

  // ---- proj: out cols w*64..+63, K=256 (128 MFMA); x1 = x + attn + pb -> x1 fp16 LDS ----
  {
    f32x4 zz = {0.f, 0.f, 0.f, 0.f};
    f32x4 pacc[4][4];
    #pragma unroll
    for (int t = 0; t < 4; ++t)
      #pragma unroll
      for (int n = 0; n < 4; ++n) pacc[t][n] = zz;
    const int swzA = (lr & 7) << 4;
    const _Float16* pwr = pwh + (size_t)(w * 64 + lr) * 256 + lk * 8;
    #pragma unroll
    for (int ks = 0; ks < 8; ++ks) {
      const int ko = ks * 64 + lk * 16;
      h8 b[4];
      #pragma unroll
      for (int nt = 0; nt < 4; ++nt) b[nt] = *(const h8*)(pwr + nt * 16 * 256 + ks * 32);
      #pragma unroll
      for (int t = 0; t < 4; ++t) {
        h8 a = *(const h8*)(smem + (((t * 16 + lr) * 512 + ko) ^ swzA));
        #pragma unroll
        for (int nt = 0; nt < 4; ++nt) pacc[t][nt] = MFMA16(a, b[nt], pacc[t][nt]);
      }
    }
    float pbv[4];
    #pragma unroll
    for (int nt = 0; nt < 4; ++nt) pbv[nt] = pb[w * 64 + nt * 16 + lr];
    #pragma unroll
    for (int t = 0; t < 4; ++t) {
      #pragma unroll
      for (int r = 0; r < 4; ++r) {
        const int tok = t * 16 + lk * 4 + r;
        const int sw = (tok & 7) << 4;
        char* xr = smem + X1_OFF + tok * 512;
        if (tok < 49) {
          const int i = tok / 7, j = tok - 7 * i;
          int rs = hb * 7 + i + 3; if (rs >= 56) rs -= 56;
          int cs = wb * 7 + j + 3; if (cs >= 56) cs -= 56;
          const size_t ro = ((size_t)bb * 3136 + rs * 56 + cs) * 256 + w * 64 + lr;
          #pragma unroll
          for (int nt = 0; nt < 4; ++nt) {
            float v = x[ro + nt * 16] + pacc[t][nt][r] + pbv[nt];
            *(_Float16*)(xr + (((w * 64 + nt * 16 + lr) * 2) ^ sw)) = (_Float16)v;
          }
        } else {
          #pragma unroll
          for (int nt = 0; nt < 4; ++nt)
            *(_Float16*)(xr + (((w * 64 + nt * 16 + lr) * 2) ^ sw)) = (_Float16)0.f;
        }
      }
    }
  }
  __syncthreads();   // b4: x1 complete; O reads done -> ZN2 may overlay O

  // ---- LN2 (reads x1 fp16) -> ZN2 fp16 @0 ----
  {
    const float4 gz = ((const float4*)g2)[lane];
    const float4 bz = ((const float4*)b2)[lane];
    for (int n = w; n < 64; n += 4) {
      const h4 ph = *(const h4*)(smem + ((X1_OFF + n * 512 + lane * 8) ^ ((n & 7) << 4)));
      float p0 = (float)ph[0], p1 = (float)ph[1], p2 = (float)ph[2], p3 = (float)ph[3];
      float mean = wsum(p0 + p1 + p2 + p3) * (1.f / 256.f);
      float d0 = p0 - mean, d1 = p1 - mean, d2 = p2 - mean, d3 = p3 - mean;
      float var = wsum(d0 * d0 + d1 * d1 + d2 * d2 + d3 * d3) * (1.f / 256.f);
      float rstd = rsqrtf(var + 1e-6f);
      h4 z;
      z[0] = (_Float16)(d0 * rstd * gz.x + bz.x);
      z[1] = (_Float16)(d1 * rstd * gz.y + bz.y);
      z[2] = (_Float16)(d2 * rstd * gz.z + bz.z);
      z[3] = (_Float16)(d3 * rstd * gz.w + bz.w);
      *(h4*)(smem + ((n * 512 + lane * 8) ^ ((n & 7) << 4))) = z;
    }
  }
  __syncthreads();   // b5: ZN2 ready

  // ---- MLP: 8 chunks of 128 hidden; wave owns 32 fc1 cols and 64 fc2 cols ----
  f32x4 zzm = {0.f, 0.f, 0.f, 0.f};
  f32x4 macc[4][4];
  #pragma unroll
  for (int t = 0; t < 4; ++t)
    #pragma unroll
    for (int n = 0; n < 4; ++n) macc[t][n] = zzm;
  const int swz = (lr & 7) << 4;

  for (int ch = 0; ch < 8; ++ch) {
    // fc1 chunk: cols ch*128 + w*32 .. +32, K=256 (64 MFMA)
    f32x4 facc[4][2];
    #pragma unroll
    for (int t = 0; t < 4; ++t) { facc[t][0] = zzm; facc[t][1] = zzm; }
    {
      const _Float16* w1p = w1h + (size_t)(ch * 128 + w * 32 + lr) * 256 + lk * 8;
      #pragma unroll
      for (int ks = 0; ks < 8; ++ks) {
        const int ko = ks * 64 + lk * 16;
        h8 b0 = *(const h8*)(w1p + ks * 32);
        h8 b1 = *(const h8*)(w1p + 16 * 256 + ks * 32);
        #pragma unroll
        for (int t = 0; t < 4; ++t) {
          h8 a = *(const h8*)(smem + (((t * 16 + lr) * 512 + ko) ^ swz));
          facc[t][0] = MFMA16(a, b0, facc[t][0]);
          facc[t][1] = MFMA16(a, b1, facc[t][1]);
        }
      }
    }
    // GELU -> H fp16 [64][256B], swz ^((tok&15)<<4)
    #pragma unroll
    for (int nt = 0; nt < 2; ++nt) {
      const float bb2 = fb1[ch * 128 + w * 32 + nt * 16 + lr];
      #pragma unroll
      for (int t = 0; t < 4; ++t) {
        #pragma unroll
        for (int r = 0; r < 4; ++r) {
          float a = facc[t][nt][r] + bb2;
          float gl = 0.5f * a * (1.f + erff(a * 0.70710678118654752f));
          const int tok = t * 16 + lk * 4 + r;
          *(_Float16*)(smem + H_OFF +
                       ((tok * 256 + (w * 32 + nt * 16 + lr) * 2) ^ ((tok & 15) << 4))) =
              (_Float16)gl;
        }
      }
    }
    __syncthreads();
    // fc2 accumulate: out cols w*64 + nt*16 + lr, K=128 (64 MFMA)
    {
      const _Float16* w2p = w2h + (size_t)(w * 64 + lr) * 1024 + ch * 128 + lk * 8;
      #pragma unroll
      for (int ks = 0; ks < 4; ++ks) {
        const int ko = ks * 64 + lk * 16;
        h8 b[4];
        #pragma unroll
        for (int nt = 0; nt < 4; ++nt) b[nt] = *(const h8*)(w2p + nt * 16 * 1024 + ks * 32);
        #pragma unroll
        for (int t = 0; t < 4; ++t) {
          h8 a = *(const h8*)(smem + H_OFF +
                              (((t * 16 + lr) * 256 + ko) ^ (((t * 16 + lr) & 15) << 4)));
          #pragma unroll
          for (int nt = 0; nt < 4; ++nt) macc[t][nt] = MFMA16(a, b[nt], macc[t][nt]);
        }
      }
    }
    __syncthreads();   // protect H before next chunk's GELU writes
  }

  // ---- epilogue: out = x1 + mlp + fb2, reverse shift (x1 cols are wave-local) ----
  {
    float bv[4];
    #pragma unroll
    for (int nt = 0; nt < 4; ++nt) bv[nt] = fb2[w * 64 + nt * 16 + lr];
    #pragma unroll
    for (int t = 0; t < 4; ++t) {
      #pragma unroll
      for (int r = 0; r < 4; ++r) {
        const int tok = t * 16 + lk * 4 + r;
        if (tok < 49) {
          const int i = tok / 7, j = tok - 7 * i;
          int rs = hb * 7 + i + 3; if (rs >= 56) rs -= 56;
          int cs = wb * 7 + j + 3; if (cs >= 56) cs -= 56;
          const size_t ro = ((size_t)bb * 3136 + rs * 56 + cs) * 256 + w * 64 + lr;
          const int sw = (tok & 7) << 4;
          const char* xr = smem + X1_OFF + tok * 512;
          #pragma unroll
          for (int nt = 0; nt < 4; ++nt) {
            float x1v = (float)(*(const _Float16*)(xr + (((w * 64 + nt * 16 + lr) * 2) ^ sw)));
            io[ro + nt * 16] = x1v + macc[t][nt][r] + bv[nt];
          }
        }
      }
    }
  }
}

extern "C" void kernel_launch(void* const* d_in, const int* in_sizes, int n_in,
                              void* d_out, int out_size, void* d_ws, size_t ws_size,
                              hipStream_t stream) {
  const float* x     = (const float*)d_in[0];
  const float* amask = (const float*)d_in[1];
  const float* g1    = (const float*)d_in[2];
  const float* b1    = (const float*)d_in[3];
  const float* qkvw  = (const float*)d_in[4];
  const float* qkvb  = (const float*)d_in[5];
  const float* temp  = (const float*)d_in[6];
  const float* rtab  = (const float*)d_in[7];
  const float* pw    = (const float*)d_in[8];
  const float* pb    = (const float*)d_in[9];
  const float* g2    = (const float*)d_in[10];
  const float* b2    = (const float*)d_in[11];
  const float* w1    = (const float*)d_in[12];
  const float* fb1   = (const float*)d_in[13];
  const float* w2    = (const float*)d_in[14];
  const float* fb2   = (const float*)d_in[15];
  const int* rpi     = (const int*)d_in[16];
  // d_in[17], d_in[18] = H, W (fixed 56)

  char* ws = (char*)d_ws;
  _Float16* wsq = (_Float16*)ws;               // 393,216 B (768x256 fp16)
  _Float16* pwh = (_Float16*)(ws + 393216);    // 131,072 B (256x256 fp16)
  _Float16* w1h = (_Float16*)(ws + 524288);    //  524,288 B (1024x256 fp16)
  _Float16* w2h = (_Float16*)(ws + 1048576);   //  524,288 B (256x1024 fp16)
  float* btab   = (float*)(ws + 1572864);      //   76,832 B (8x2401 f32)
  float* io = (float*)d_out;

  k_prep_qkv<<<768, 256, 0, stream>>>(qkvw, wsq);
  k_prep_pw<<<256, 256, 0, stream>>>(pw, pwh);
  k_prep_w1<<<1024, 256, 0, stream>>>(w1, w1h);
  k_prep_w2<<<1024, 256, 0, stream>>>(w2, w2h);
  k_prep_btab<<<10, 256, 0, stream>>>(rpi, rtab, btab);
  k_blk<<<2048, 256, 0, stream>>>(x, wsq, pwh, qkvb, g1, b1, temp, btab,
                                  amask, pb, g2, b2, w1h, fb1, w2h, fb2, io);
}

// Round 12
// 944.994 us; speedup vs baseline: 1.1186x; 1.1186x over previous
//
#include <hip/hip_runtime.h>

typedef unsigned short u16;
typedef unsigned int u32;
typedef _Float16 h4 __attribute__((ext_vector_type(4)));
typedef _Float16 h8 __attribute__((ext_vector_type(8)));
typedef float f32x4 __attribute__((ext_vector_type(4)));

#define MFMA16(a, b, c) __builtin_amdgcn_mfma_f32_16x16x32_f16((a), (b), (c), 0, 0, 0)

__device__ __forceinline__ float wsum(float v) {
  #pragma unroll
  for (int o = 32; o > 0; o >>= 1) v += __shfl_down(v, o);
  return __shfl(v, 0);
}

// ---------- prep: qkv_w f32 [256k][768c] -> fp16 [row = h*96 + mat*32 + cc][256 k] ----------
__global__ void k_prep_qkv(const float* __restrict__ w, _Float16* __restrict__ o) {
  const int e = blockIdx.x * 256 + threadIdx.x;   // 768*256
  const int r = e >> 8, k = e & 255;
  const int h = r / 96, rem = r - h * 96;
  const int mat = rem >> 5, cc = rem & 31;
  o[e] = (_Float16)w[k * 768 + mat * 256 + h * 32 + cc];
}

// ---------- prep: proj_w f32 [256 in][256 out] -> fp16 [out][in] (k-contiguous) ----------
__global__ void k_prep_pw(const float* __restrict__ w, _Float16* __restrict__ o) {
  const int e = blockIdx.x * 256 + threadIdx.x;   // 256*256
  const int oc = e >> 8, ic = e & 255;
  o[e] = (_Float16)w[ic * 256 + oc];
}

// ---------- prep: fc1_w f32 [256k][1024c] -> fp16 [col][256 k] ----------
__global__ void k_prep_w1(const float* __restrict__ w, _Float16* __restrict__ o) {
  const int e = blockIdx.x * 256 + threadIdx.x;   // 1024*256
  const int col = e >> 8, k = e & 255;
  o[e] = (_Float16)w[k * 1024 + col];
}

// ---------- prep: fc2_w f32 [1024k][256c] -> fp16 [col][1024 k] ----------
__global__ void k_prep_w2(const float* __restrict__ w, _Float16* __restrict__ o) {
  const int e = blockIdx.x * 256 + threadIdx.x;   // 256*1024
  const int oc = e >> 10, k = e & 1023;
  o[e] = (_Float16)w[k * 256 + oc];
}

// ---------- prep: btab[h][e] = rtab[rpi[e]*8 + h] ----------
__global__ void k_prep_btab(const int* __restrict__ rpi, const float* __restrict__ rtab,
                            float* __restrict__ btab) {
  const int e = blockIdx.x * 256 + threadIdx.x;
  if (e < 2401) {
    const int idx = rpi[e];
    #pragma unroll
    for (int h = 0; h < 8; ++h) btab[h * 2401 + e] = rtab[idx * 8 + h];
  }
}

// ---------- fused block kernel: 2048 blocks x 256 threads (4 waves), 80 KiB -> 2 blocks/CU ----
// Wave w handles heads {w, w+4} sequentially, fully inlined (no lambda / array-by-ref:
// R9's lambda forced oA/oB + accumulators into scratch -> 600 MB spill traffic).
// Head A's PV output parks as fp16 (16 VGPRs); head B's stays f32 until the O-write.
// Phase A:
//   ZN   [0,32768)      : LN1 out fp16 [64][512B], swz ^((row&7)<<4). O overlays after b2.
//   priv 32768+w*12288  : Q(4K)/K(4K)/V(4K) per wave; P overlays Q+K. Reused across 2 heads.
// Phase B:
//   ZN2  [0,32768)      : LN2 out fp16 (over dead O)
//   x1   [32768,65536)  : fp16 [64][512B] swz ^((tok&7)<<4) (over dead priv)
//   H    [65536,81920)  : fp16 [64][256B] swz ^((tok&15)<<4), hidden chunk = 128
#define X1_OFF 32768
#define H_OFF  65536

__global__ __launch_bounds__(256, 2) void k_blk(
    const float* __restrict__ x, const _Float16* __restrict__ wsq,
    const _Float16* __restrict__ pwh, const float* __restrict__ qkvb,
    const float* __restrict__ g1, const float* __restrict__ b1,
    const float* __restrict__ temp, const float* __restrict__ btab,
    const float* __restrict__ amask, const float* __restrict__ pb,
    const float* __restrict__ g2, const float* __restrict__ b2,
    const _Float16* __restrict__ w1h, const float* __restrict__ fb1,
    const _Float16* __restrict__ w2h, const float* __restrict__ fb2,
    float* __restrict__ io) {
  __shared__ __align__(16) char smem[81920];
  const int tid = threadIdx.x;
  const int lane = tid & 63, w = tid >> 6;      // w = 0..3
  const int lr = lane & 15, lk = lane >> 4;
  const int win = blockIdx.x;
  const int bb = win >> 6, wimg = win & 63;
  const int hb = wimg >> 3, wb = wimg & 7;
  const float scale = expf(temp[0]);
  char* const pwv = smem + 32768 + w * 12288;   // wave-private scratch (phase A)

  // --- LN1 at shifted source coords (roll(-3)) -> ZN fp16 ---
  {
    const float4 gz = ((const float4*)g1)[lane];
    const float4 bz = ((const float4*)b1)[lane];
    for (int n = w; n < 49; n += 4) {
      int i = n / 7, j = n - 7 * i;
      int rs = hb * 7 + i + 3; if (rs >= 56) rs -= 56;
      int cs = wb * 7 + j + 3; if (cs >= 56) cs -= 56;
      const float4 p = ((const float4*)(x + ((size_t)bb * 3136 + rs * 56 + cs) * 256))[lane];
      float mean = wsum(p.x + p.y + p.z + p.w) * (1.f / 256.f);
      float d0 = p.x - mean, d1 = p.y - mean, d2 = p.z - mean, d3 = p.w - mean;
      float var = wsum(d0 * d0 + d1 * d1 + d2 * d2 + d3 * d3) * (1.f / 256.f);
      float rstd = rsqrtf(var + 1e-6f);
      h4 z;
      z[0] = (_Float16)(d0 * rstd * gz.x + bz.x);
      z[1] = (_Float16)(d1 * rstd * gz.y + bz.y);
      z[2] = (_Float16)(d2 * rstd * gz.z + bz.z);
      z[3] = (_Float16)(d3 * rstd * gz.w + bz.w);
      *(h4*)(smem + ((n * 512 + lane * 8) ^ ((n & 7) << 4))) = z;
    }
  }
  __syncthreads();   // b1: ZN ready

  h4 pka0[4], pka1[4];        // head A PV output, parked as fp16 (16 VGPRs)
  f32x4 hb0[4], hb1[4];       // head B PV output (lives only until the O-write)

  // =================== HEAD A (h = w) ===================
  {
    const int h = w;
    f32x4 zz = {0.f, 0.f, 0.f, 0.f};
    // qkv: (64x256)@(256x96), 192 MFMA
    {
      f32x4 acc[4][6];
      #pragma unroll
      for (int t = 0; t < 4; ++t)
        #pragma unroll
        for (int c = 0; c < 6; ++c) acc[t][c] = zz;
      const _Float16* wr[6];
      #pragma unroll
      for (int c = 0; c < 6; ++c)
        wr[c] = wsq + ((size_t)(h * 96 + c * 16 + lr) * 256 + lk * 8);
      const int swzA = (lr & 7) << 4;
      #pragma unroll
      for (int ks = 0; ks < 8; ++ks) {
        const int ko = ks * 64 + lk * 16;
        h8 a[4];
        #pragma unroll
        for (int t = 0; t < 4; ++t)
          a[t] = *(const h8*)(smem + (((t * 16 + lr) * 512 + ko) ^ swzA));
        h8 b[6];
        #pragma unroll
        for (int c = 0; c < 6; ++c) b[c] = *(const h8*)(wr[c] + ks * 32);
        #pragma unroll
        for (int t = 0; t < 4; ++t)
          #pragma unroll
          for (int c = 0; c < 6; ++c) acc[t][c] = MFMA16(a[t], b[c], acc[t][c]);
      }
      #pragma unroll
      for (int c = 0; c < 6; ++c) {
        const int mat = c >> 1;
        const int cc = (c & 1) * 16 + lr;
        const float bias = qkvb[mat * 256 + h * 32 + cc];
        #pragma unroll
        for (int t = 0; t < 4; ++t) {
          const int tok0 = t * 16 + lk * 4;
          if (mat == 2) {
            h4 pk;
            #pragma unroll
            for (int r = 0; r < 4; ++r) {
              float v = (tok0 + r < 49) ? (acc[t][c][r] + bias) : 0.f;
              pk[r] = (_Float16)v;
            }
            *(h4*)(pwv + 8192 + (tok0 >> 3) * 512 + cc * 16 + (tok0 & 7) * 2) = pk;
          } else {
            char* base = pwv + (mat ? 4096 : 0);
            const float mult = mat ? 1.f : scale;
            #pragma unroll
            for (int r = 0; r < 4; ++r) {
              const int tok = tok0 + r;
              float v = (tok < 49) ? (acc[t][c][r] + bias) * mult : 0.f;
              *(_Float16*)(base + ((tok * 64 + cc * 2) ^ (((tok >> 1) & 3) << 4))) = (_Float16)v;
            }
          }
        }
      }
    }
    // scores + in-register softmax -> P
    {
      f32x4 s[4][4];
      #pragma unroll
      for (int t = 0; t < 4; ++t)
        #pragma unroll
        for (int m = 0; m < 4; ++m) s[t][m] = zz;
      const int swzq = ((lr >> 1) & 3) << 4;
      h8 aq[4], bk[4];
      #pragma unroll
      for (int t = 0; t < 4; ++t) {
        aq[t] = *(const h8*)(pwv + (((t * 16 + lr) * 64 + lk * 16) ^ swzq));
        bk[t] = *(const h8*)(pwv + 4096 + (((t * 16 + lr) * 64 + lk * 16) ^ swzq));
      }
      #pragma unroll
      for (int t = 0; t < 4; ++t)
        #pragma unroll
        for (int m = 0; m < 4; ++m) s[t][m] = MFMA16(aq[t], bk[m], s[t][m]);

      const float* bt = btab + (size_t)h * 2401;
      const float* am = amask + (size_t)wimg * 2401;
      #pragma unroll
      for (int t = 0; t < 4; ++t) {
        #pragma unroll
        for (int r = 0; r < 4; ++r) {
          const int n = t * 16 + lk * 4 + r;
          if (n < 49) {
            #pragma unroll
            for (int m = 0; m < 4; ++m) {
              const int mm = m * 16 + lr;
              float sv;
              if (mm >= 49) sv = -1e38f;
              else {
                sv = s[t][m][r];
                if (mm == n) sv = -1e30f;
                const int ee = n * 49 + mm;
                sv += bt[ee] + am[ee];
              }
              s[t][m][r] = sv;
            }
          } else {
            #pragma unroll
            for (int m = 0; m < 4; ++m) s[t][m][r] = 0.f;
          }
        }
      }
      #pragma unroll
      for (int t = 0; t < 4; ++t) {
        #pragma unroll
        for (int r = 0; r < 4; ++r) {
          float mx = fmaxf(fmaxf(s[t][0][r], s[t][1][r]), fmaxf(s[t][2][r], s[t][3][r]));
          mx = fmaxf(mx, __shfl_xor(mx, 1));
          mx = fmaxf(mx, __shfl_xor(mx, 2));
          mx = fmaxf(mx, __shfl_xor(mx, 4));
          mx = fmaxf(mx, __shfl_xor(mx, 8));
          float e0 = expf(s[t][0][r] - mx), e1 = expf(s[t][1][r] - mx);
          float e2 = expf(s[t][2][r] - mx), e3 = expf(s[t][3][r] - mx);
          float sm = e0 + e1 + e2 + e3;
          sm += __shfl_xor(sm, 1);
          sm += __shfl_xor(sm, 2);
          sm += __shfl_xor(sm, 4);
          sm += __shfl_xor(sm, 8);
          const float inv = 1.f / sm;
          const int n = t * 16 + lk * 4 + r;
          const int sw = (n & 7) << 4;
          char* pr = pwv + n * 128;
          *(_Float16*)(pr + ((lr * 2) ^ sw))        = (_Float16)(e0 * inv);
          *(_Float16*)(pr + (((16 + lr) * 2) ^ sw)) = (_Float16)(e1 * inv);
          *(_Float16*)(pr + (((32 + lr) * 2) ^ sw)) = (_Float16)(e2 * inv);
          *(_Float16*)(pr + (((48 + lr) * 2) ^ sw)) = (_Float16)(e3 * inv);
        }
      }
    }
    // PV -> park as fp16
    {
      f32x4 o0[4], o1[4];
      #pragma unroll
      for (int t = 0; t < 4; ++t) { o0[t] = zz; o1[t] = zz; }
      const int swzp = (lr & 7) << 4;
      #pragma unroll
      for (int ks = 0; ks < 2; ++ks) {
        h8 bv0 = *(const h8*)(pwv + 8192 + (ks * 4 + lk) * 512 + lr * 16);
        h8 bv1 = *(const h8*)(pwv + 8192 + (ks * 4 + lk) * 512 + (16 + lr) * 16);
        #pragma unroll
        for (int t = 0; t < 4; ++t) {
          h8 ap = *(const h8*)(pwv + (((t * 16 + lr) * 128 + ks * 64 + lk * 16) ^ swzp));
          o0[t] = MFMA16(ap, bv0, o0[t]);
          o1[t] = MFMA16(ap, bv1, o1[t]);
        }
      }
      #pragma unroll
      for (int t = 0; t < 4; ++t) {
        #pragma unroll
        for (int r = 0; r < 4; ++r) {
          pka0[t][r] = (_Float16)o0[t][r];
          pka1[t][r] = (_Float16)o1[t][r];
        }
      }
    }
  }

  // =================== HEAD B (h = w + 4) ===================
  {
    const int h = w + 4;
    f32x4 zz = {0.f, 0.f, 0.f, 0.f};
    // qkv
    {
      f32x4 acc[4][6];
      #pragma unroll
      for (int t = 0; t < 4; ++t)
        #pragma unroll
        for (int c = 0; c < 6; ++c) acc[t][c] = zz;
      const _Float16* wr[6];
      #pragma unroll
      for (int c = 0; c < 6; ++c)
        wr[c] = wsq + ((size_t)(h * 96 + c * 16 + lr) * 256 + lk * 8);
      const int swzA = (lr & 7) << 4;
      #pragma unroll
      for (int ks = 0; ks < 8; ++ks) {
        const int ko = ks * 64 + lk * 16;
        h8 a[4];
        #pragma unroll
        for (int t = 0; t < 4; ++t)
          a[t] = *(const h8*)(smem + (((t * 16 + lr) * 512 + ko) ^ swzA));
        h8 b[6];
        #pragma unroll
        for (int c = 0; c < 6; ++c) b[c] = *(const h8*)(wr[c] + ks * 32);
        #pragma unroll
        for (int t = 0; t < 4; ++t)
          #pragma unroll
          for (int c = 0; c < 6; ++c) acc[t][c] = MFMA16(a[t], b[c], acc[t][c]);
      }
      #pragma unroll
      for (int c = 0; c < 6; ++c) {
        const int mat = c >> 1;
        const int cc = (c & 1) * 16 + lr;
        const float bias = qkvb[mat * 256 + h * 32 + cc];
        #pragma unroll
        for (int t = 0; t < 4; ++t) {
          const int tok0 = t * 16 + lk * 4;
          if (mat == 2) {
            h4 pk;
            #pragma unroll
            for (int r = 0; r < 4; ++r) {
              float v = (tok0 + r < 49) ? (acc[t][c][r] + bias) : 0.f;
              pk[r] = (_Float16)v;
            }
            *(h4*)(pwv + 8192 + (tok0 >> 3) * 512 + cc * 16 + (tok0 & 7) * 2) = pk;
          } else {
            char* base = pwv + (mat ? 4096 : 0);
            const float mult = mat ? 1.f : scale;
            #pragma unroll
            for (int r = 0; r < 4; ++r) {
              const int tok = tok0 + r;
              float v = (tok < 49) ? (acc[t][c][r] + bias) * mult : 0.f;
              *(_Float16*)(base + ((tok * 64 + cc * 2) ^ (((tok >> 1) & 3) << 4))) = (_Float16)v;
            }
          }
        }
      }
    }
    // scores + softmax -> P
    {
      f32x4 s[4][4];
      #pragma unroll
      for (int t = 0; t < 4; ++t)
        #pragma unroll
        for (int m = 0; m < 4; ++m) s[t][m] = zz;
      const int swzq = ((lr >> 1) & 3) << 4;
      h8 aq[4], bk[4];
      #pragma unroll
      for (int t = 0; t < 4; ++t) {
        aq[t] = *(const h8*)(pwv + (((t * 16 + lr) * 64 + lk * 16) ^ swzq));
        bk[t] = *(const h8*)(pwv + 4096 + (((t * 16 + lr) * 64 + lk * 16) ^ swzq));
      }
      #pragma unroll
      for (int t = 0; t < 4; ++t)
        #pragma unroll
        for (int m = 0; m < 4; ++m) s[t][m] = MFMA16(aq[t], bk[m], s[t][m]);

      const float* bt = btab + (size_t)h * 2401;
      const float* am = amask + (size_t)wimg * 2401;
      #pragma unroll
      for (int t = 0; t < 4; ++t) {
        #pragma unroll
        for (int r = 0; r < 4; ++r) {
          const int n = t * 16 + lk * 4 + r;
          if (n < 49) {
            #pragma unroll
            for (int m = 0; m < 4; ++m) {
              const int mm = m * 16 + lr;
              float sv;
              if (mm >= 49) sv = -1e38f;
              else {
                sv = s[t][m][r];
                if (mm == n) sv = -1e30f;
                const int ee = n * 49 + mm;
                sv += bt[ee] + am[ee];
              }
              s[t][m][r] = sv;
            }
          } else {
            #pragma unroll
            for (int m = 0; m < 4; ++m) s[t][m][r] = 0.f;
          }
        }
      }
      #pragma unroll
      for (int t = 0; t < 4; ++t) {
        #pragma unroll
        for (int r = 0; r < 4; ++r) {
          float mx = fmaxf(fmaxf(s[t][0][r], s[t][1][r]), fmaxf(s[t][2][r], s[t][3][r]));
          mx = fmaxf(mx, __shfl_xor(mx, 1));
          mx = fmaxf(mx, __shfl_xor(mx, 2));
          mx = fmaxf(mx, __shfl_xor(mx, 4));
          mx = fmaxf(mx, __shfl_xor(mx, 8));
          float e0 = expf(s[t][0][r] - mx), e1 = expf(s[t][1][r] - mx);
          float e2 = expf(s[t][2][r] - mx), e3 = expf(s[t][3][r] - mx);
          float sm = e0 + e1 + e2 + e3;
          sm += __shfl_xor(sm, 1);
          sm += __shfl_xor(sm, 2);
          sm += __shfl_xor(sm, 4);
          sm += __shfl_xor(sm, 8);
          const float inv = 1.f / sm;
          const int n = t * 16 + lk * 4 + r;
          const int sw = (n & 7) << 4;
          char* pr = pwv + n * 128;
          *(_Float16*)(pr + ((lr * 2) ^ sw))        = (_Float16)(e0 * inv);
          *(_Float16*)(pr + (((16 + lr) * 2) ^ sw)) = (_Float16)(e1 * inv);
          *(_Float16*)(pr + (((32 + lr) * 2) ^ sw)) = (_Float16)(e2 * inv);
          *(_Float16*)(pr + (((48 + lr) * 2) ^ sw)) = (_Float16)(e3 * inv);
        }
      }
    }
    // PV -> hb0/hb1 (f32, function scope)
    {
      #pragma unroll
      for (int t = 0; t < 4; ++t) { hb0[t] = zz; hb1[t] = zz; }
      const int swzp = (lr & 7) << 4;
      #pragma unroll
      for (int ks = 0; ks < 2; ++ks) {
        h8 bv0 = *(const h8*)(pwv + 8192 + (ks * 4 + lk) * 512 + lr * 16);
        h8 bv1 = *(const h8*)(pwv + 8192 + (ks * 4 + lk) * 512 + (16 + lr) * 16);
        #pragma unroll
        for (int t = 0; t < 4; ++t) {
          h8 ap = *(const h8*)(pwv + (((t * 16 + lr) * 128 + ks * 64 + lk * 16) ^ swzp));
          hb0[t] = MFMA16(ap, bv0, hb0[t]);
          hb1[t] = MFMA16(ap, bv1, hb1[t]);
        }
      }
    }
  }
  __syncthreads();   // b2: all ZN reads done -> O may overlay ZN

  // ---- write both heads' O slices into shared O [64][512B] (ZN region) ----
  #pragma unroll
  for (int t = 0; t < 4; ++t) {
    #pragma unroll
    for (int r = 0; r < 4; ++r) {
      const int tok = t * 16 + lk * 4 + r;
      const int sw = (tok & 7) << 4;
      char* orow = smem + tok * 512;
      // head A (cols w*32 .. +32), parked fp16
      *(_Float16*)(orow + (((w * 32 + lr) * 2) ^ sw))        = pka0[t][r];
      *(_Float16*)(orow + (((w * 32 + 16 + lr) * 2) ^ sw))   = pka1[t][r];
      // head B (cols (w+4)*32 .. +32 = w*32+128 ..)
      *(_Float16*)(orow + (((w * 32 + 128 + lr) * 2) ^ sw))      = (_Float16)hb0[t][r];
      *(_Float16*)(orow + (((w * 32 + 144 + lr) * 2) ^ sw))      = (_Float16)hb1[t][r];
    }
  }
  __syncthreads();   // b3: full O ready; priv dead

  // ---- proj: out cols w*64..+63, K=256 (128 MFMA); x1 = x + attn + pb -> x1 fp16 LDS ----
  {
    f32x4 zz = {0.f, 0.f, 0.f, 0.f};
    f32x4 pacc[4][4];
    #pragma unroll
    for (int t = 0; t < 4; ++t)
      #pragma unroll
      for (int n = 0; n < 4; ++n) pacc[t][n] = zz;
    const int swzA = (lr & 7) << 4;
    const _Float16* pwr = pwh + (size_t)(w * 64 + lr) * 256 + lk * 8;
    #pragma unroll
    for (int ks = 0; ks < 8; ++ks) {
      const int ko = ks * 64 + lk * 16;
      h8 b[4];
      #pragma unroll
      for (int nt = 0; nt < 4; ++nt) b[nt] = *(const h8*)(pwr + nt * 16 * 256 + ks * 32);
      #pragma unroll
      for (int t = 0; t < 4; ++t) {
        h8 a = *(const h8*)(smem + (((t * 16 + lr) * 512 + ko) ^ swzA));
        #pragma unroll
        for (int nt = 0; nt < 4; ++nt) pacc[t][nt] = MFMA16(a, b[nt], pacc[t][nt]);
      }
    }
    float pbv[4];
    #pragma unroll
    for (int nt = 0; nt < 4; ++nt) pbv[nt] = pb[w * 64 + nt * 16 + lr];
    #pragma unroll
    for (int t = 0; t < 4; ++t) {
      #pragma unroll
      for (int r = 0; r < 4; ++r) {
        const int tok = t * 16 + lk * 4 + r;
        const int sw = (tok & 7) << 4;
        char* xr = smem + X1_OFF + tok * 512;
        if (tok < 49) {
          const int i = tok / 7, j = tok - 7 * i;
          int rs = hb * 7 + i + 3; if (rs >= 56) rs -= 56;
          int cs = wb * 7 + j + 3; if (cs >= 56) cs -= 56;
          const size_t ro = ((size_t)bb * 3136 + rs * 56 + cs) * 256 + w * 64 + lr;
          #pragma unroll
          for (int nt = 0; nt < 4; ++nt) {
            float v = x[ro + nt * 16] + pacc[t][nt][r] + pbv[nt];
            *(_Float16*)(xr + (((w * 64 + nt * 16 + lr) * 2) ^ sw)) = (_Float16)v;
          }
        } else {
          #pragma unroll
          for (int nt = 0; nt < 4; ++nt)
            *(_Float16*)(xr + (((w * 64 + nt * 16 + lr) * 2) ^ sw)) = (_Float16)0.f;
        }
      }
    }
  }
  __syncthreads();   // b4: x1 complete; O reads done -> ZN2 may overlay O

  // ---- LN2 (reads x1 fp16) -> ZN2 fp16 @0 ----
  {
    const float4 gz = ((const float4*)g2)[lane];
    const float4 bz = ((const float4*)b2)[lane];
    for (int n = w; n < 64; n += 4) {
      const h4 ph = *(const h4*)(smem + ((X1_OFF + n * 512 + lane * 8) ^ ((n & 7) << 4)));
      float p0 = (float)ph[0], p1 = (float)ph[1], p2 = (float)ph[2], p3 = (float)ph[3];
      float mean = wsum(p0 + p1 + p2 + p3) * (1.f / 256.f);
      float d0 = p0 - mean, d1 = p1 - mean, d2 = p2 - mean, d3 = p3 - mean;
      float var = wsum(d0 * d0 + d1 * d1 + d2 * d2 + d3 * d3) * (1.f / 256.f);
      float rstd = rsqrtf(var + 1e-6f);
      h4 z;
      z[0] = (_Float16)(d0 * rstd * gz.x + bz.x);
      z[1] = (_Float16)(d1 * rstd * gz.y + bz.y);
      z[2] = (_Float16)(d2 * rstd * gz.z + bz.z);
      z[3] = (_Float16)(d3 * rstd * gz.w + bz.w);
      *(h4*)(smem + ((n * 512 + lane * 8) ^ ((n & 7) << 4))) = z;
    }
  }
  __syncthreads();   // b5: ZN2 ready

  // ---- MLP: 8 chunks of 128 hidden; wave owns 32 fc1 cols and 64 fc2 cols ----
  f32x4 zzm = {0.f, 0.f, 0.f, 0.f};
  f32x4 macc[4][4];
  #pragma unroll
  for (int t = 0; t < 4; ++t)
    #pragma unroll
    for (int n = 0; n < 4; ++n) macc[t][n] = zzm;
  const int swz = (lr & 7) << 4;

  for (int ch = 0; ch < 8; ++ch) {
    f32x4 facc[4][2];
    #pragma unroll
    for (int t = 0; t < 4; ++t) { facc[t][0] = zzm; facc[t][1] = zzm; }
    {
      const _Float16* w1p = w1h + (size_t)(ch * 128 + w * 32 + lr) * 256 + lk * 8;
      #pragma unroll
      for (int ks = 0; ks < 8; ++ks) {
        const int ko = ks * 64 + lk * 16;
        h8 b0 = *(const h8*)(w1p + ks * 32);
        h8 b1 = *(const h8*)(w1p + 16 * 256 + ks * 32);
        #pragma unroll
        for (int t = 0; t < 4; ++t) {
          h8 a = *(const h8*)(smem + (((t * 16 + lr) * 512 + ko) ^ swz));
          facc[t][0] = MFMA16(a, b0, facc[t][0]);
          facc[t][1] = MFMA16(a, b1, facc[t][1]);
        }
      }
    }
    // GELU -> H fp16 [64][256B], swz ^((tok&15)<<4)
    #pragma unroll
    for (int nt = 0; nt < 2; ++nt) {
      const float bb2 = fb1[ch * 128 + w * 32 + nt * 16 + lr];
      #pragma unroll
      for (int t = 0; t < 4; ++t) {
        #pragma unroll
        for (int r = 0; r < 4; ++r) {
          float a = facc[t][nt][r] + bb2;
          float gl = 0.5f * a * (1.f + erff(a * 0.70710678118654752f));
          const int tok = t * 16 + lk * 4 + r;
          *(_Float16*)(smem + H_OFF +
                       ((tok * 256 + (w * 32 + nt * 16 + lr) * 2) ^ ((tok & 15) << 4))) =
              (_Float16)gl;
        }
      }
    }
    __syncthreads();
    // fc2 accumulate: out cols w*64 + nt*16 + lr, K=128
    {
      const _Float16* w2p = w2h + (size_t)(w * 64 + lr) * 1024 + ch * 128 + lk * 8;
      #pragma unroll
      for (int ks = 0; ks < 4; ++ks) {
        const int ko = ks * 64 + lk * 16;
        h8 b[4];
        #pragma unroll
        for (int nt = 0; nt < 4; ++nt) b[nt] = *(const h8*)(w2p + nt * 16 * 1024 + ks * 32);
        #pragma unroll
        for (int t = 0; t < 4; ++t) {
          h8 a = *(const h8*)(smem + H_OFF +
                              (((t * 16 + lr) * 256 + ko) ^ (((t * 16 + lr) & 15) << 4)));
          #pragma unroll
          for (int nt = 0; nt < 4; ++nt) macc[t][nt] = MFMA16(a, b[nt], macc[t][nt]);
        }
      }
    }
    __syncthreads();
  }

  // ---- epilogue: out = x1 + mlp + fb2, reverse shift ----
  {
    float bv[4];
    #pragma unroll
    for (int nt = 0; nt < 4; ++nt) bv[nt] = fb2[w * 64 + nt * 16 + lr];
    #pragma unroll
    for (int t = 0; t < 4; ++t) {
      #pragma unroll
      for (int r = 0; r < 4; ++r) {
        const int tok = t * 16 + lk * 4 + r;
        if (tok < 49) {
          const int i = tok / 7, j = tok - 7 * i;
          int rs = hb * 7 + i + 3; if (rs >= 56) rs -= 56;
          int cs = wb * 7 + j + 3; if (cs >= 56) cs -= 56;
          const size_t ro = ((size_t)bb * 3136 + rs * 56 + cs) * 256 + w * 64 + lr;
          const int sw = (tok & 7) << 4;
          const char* xr = smem + X1_OFF + tok * 512;
          #pragma unroll
          for (int nt = 0; nt < 4; ++nt) {
            float x1v = (float)(*(const _Float16*)(xr + (((w * 64 + nt * 16 + lr) * 2) ^ sw)));
            io[ro + nt * 16] = x1v + macc[t][nt][r] + bv[nt];
          }
        }
      }
    }
  }
}

extern "C" void kernel_launch(void* const* d_in, const int* in_sizes, int n_in,
                              void* d_out, int out_size, void* d_ws, size_t ws_size,
                              hipStream_t stream) {
  const float* x     = (const float*)d_in[0];
  const float* amask = (const float*)d_in[1];
  const float* g1    = (const float*)d_in[2];
  const float* b1    = (const float*)d_in[3];
  const float* qkvw  = (const float*)d_in[4];
  const float* qkvb  = (const float*)d_in[5];
  const float* temp  = (const float*)d_in[6];
  const float* rtab  = (const float*)d_in[7];
  const float* pw    = (const float*)d_in[8];
  const float* pb    = (const float*)d_in[9];
  const float* g2    = (const float*)d_in[10];
  const float* b2    = (const float*)d_in[11];
  const float* w1    = (const float*)d_in[12];
  const float* fb1   = (const float*)d_in[13];
  const float* w2    = (const float*)d_in[14];
  const float* fb2   = (const float*)d_in[15];
  const int* rpi     = (const int*)d_in[16];
  // d_in[17], d_in[18] = H, W (fixed 56)

  char* ws = (char*)d_ws;
  _Float16* wsq = (_Float16*)ws;               // 393,216 B (768x256 fp16)
  _Float16* pwh = (_Float16*)(ws + 393216);    // 131,072 B (256x256 fp16)
  _Float16* w1h = (_Float16*)(ws + 524288);    //  524,288 B (1024x256 fp16)
  _Float16* w2h = (_Float16*)(ws + 1048576);   //  524,288 B (256x1024 fp16)
  float* btab   = (float*)(ws + 1572864);      //   76,832 B (8x2401 f32)
  float* io = (float*)d_out;

  k_prep_qkv<<<768, 256, 0, stream>>>(qkvw, wsq);
  k_prep_pw<<<256, 256, 0, stream>>>(pw, pwh);
  k_prep_w1<<<1024, 256, 0, stream>>>(w1, w1h);
  k_prep_w2<<<1024, 256, 0, stream>>>(w2, w2h);
  k_prep_btab<<<10, 256, 0, stream>>>(rpi, rtab, btab);
  k_blk<<<2048, 256, 0, stream>>>(x, wsq, pwh, qkvb, g1, b1, temp, btab,
                                  amask, pb, g2, b2, w1h, fb1, w2h, fb2, io);
}